// Round 4
// baseline (2136.043 us; speedup 1.0000x reference)
//
#include <hip/hip_runtime.h>

#define HH 512
#define WW 512
#define HWSZ (HH * WW)

// LDS layout (float offsets). All float4-group bases are 16B-aligned.
#define O_W1 0      // 7x16
#define O_B1 112    // 16
#define O_W2 128    // 16x16
#define O_B2 384    // 16
#define O_W3 400    // 16x16
#define O_B3 656    // 16
#define O_W4 672    // 16x16
#define O_B4 928    // 16
#define O_W5 944    // 16x4 (padded from 16x3)
#define O_B5 1008   // 4 (padded from 3)
#define SW_TOT 1012

// ---------------------------------------------------------------------------
// Pre-pass: transpose featuremap (C,H,W) -> (H,W,C): one bilinear corner = one
// aligned float4 load.
// ---------------------------------------------------------------------------
__global__ void fm_transpose(const float* __restrict__ fm, float* __restrict__ fmT) {
    int i = blockIdx.x * blockDim.x + threadIdx.x;
    if (i < HWSZ) {
        float4 v;
        v.x = fm[i];
        v.y = fm[HWSZ + i];
        v.z = fm[2 * HWSZ + i];
        v.w = fm[3 * HWSZ + i];
        reinterpret_cast<float4*>(fmT)[i] = v;
    }
}

// ---------------------------------------------------------------------------
// Fused grid_sample + MLP, 2 points/thread.
// Weights staged in LDS, read via uniform-address ds_read_b128 (broadcast:
// conflict-free, ~2-4 cyc, and structurally CANNOT be scalarized into SGPRs —
// R1/R3 showed global weight reads become s_load -> SGPR cap 112 -> spill
// machinery: R1 v_writelane SGPR-spill (745us), R3 fenced chunks -> VGPR=32
// with activations demoted to AGPRs + v_accvgpr shuffling (278us, 4.5x VALU
// bloat). LDS reads land in VGPRs; one float4 read feeds 8 FMAs (4 cols x
// 2 pts).
// NO min-occupancy launch bound: R2's (256,4) capped VGPRs at 64 and demoted
// activation arrays to scratch (11.8 GB HBM, 3160us). Plain 256-thread cap
// leaves the allocator 256 VGPRs — activations stay in VGPRs.
// ---------------------------------------------------------------------------
template <bool TR>
__global__ __launch_bounds__(256) void mlp_fused(
    const float* __restrict__ x, const float* __restrict__ fm,
    const float* __restrict__ W1, const float* __restrict__ b1,
    const float* __restrict__ W2, const float* __restrict__ b2,
    const float* __restrict__ W3, const float* __restrict__ b3,
    const float* __restrict__ W4, const float* __restrict__ b4,
    const float* __restrict__ W5, const float* __restrict__ b5,
    float* __restrict__ out, int n)
{
    __shared__ __align__(16) float sW[SW_TOT];
    const int tid = threadIdx.x;

    // ---- stage weights into LDS (one pass; 256 threads) ----
    if (tid < 112) sW[O_W1 + tid] = W1[tid];
    if (tid < 16) {
        sW[O_B1 + tid] = b1[tid];
        sW[O_B2 + tid] = b2[tid];
        sW[O_B3 + tid] = b3[tid];
        sW[O_B4 + tid] = b4[tid];
    }
    {   // W2/W3/W4: exactly one element per thread
        sW[O_W2 + tid] = W2[tid];
        sW[O_W3 + tid] = W3[tid];
        sW[O_W4 + tid] = W4[tid];
    }
    if (tid < 64) {  // W5 padded 16x3 -> 16x4
        int r = tid >> 2, c = tid & 3;
        sW[O_W5 + tid] = (c < 3) ? W5[r * 3 + c] : 0.f;
    }
    if (tid < 4) sW[O_B5 + tid] = (tid < 3) ? b5[tid] : 0.f;
    __syncthreads();

    const long long t  = (long long)blockIdx.x * blockDim.x + tid;
    const long long i0 = 2 * t;
    if (i0 >= n) return;  // after the barrier: safe
    const bool have2 = (i0 + 1 < n);

    // ---- load 2 points' coords ----
    float px[2][3];
    if (have2) {
        const float2* x2 = reinterpret_cast<const float2*>(x);
        float2 a = x2[3 * t], b = x2[3 * t + 1], c = x2[3 * t + 2];
        px[0][0] = a.x; px[0][1] = a.y; px[0][2] = b.x;
        px[1][0] = b.y; px[1][1] = c.x; px[1][2] = c.y;
    } else {
        px[0][0] = x[3 * i0]; px[0][1] = x[3 * i0 + 1]; px[0][2] = x[3 * i0 + 2];
        px[1][0] = px[0][0];  px[1][1] = px[0][1];      px[1][2] = px[0][2];
    }

    // ---- bilinear sample, border clamp (identical arithmetic to reference) ----
    float feat[2][4];
#pragma unroll
    for (int p = 0; p < 2; ++p) {
        float gx = px[p][0] * 2.f - 1.f;
        float gy = px[p][1] * 2.f - 1.f;
        float fx = ((gx + 1.f) * (float)WW - 1.f) * 0.5f;
        float fy = ((gy + 1.f) * (float)HH - 1.f) * 0.5f;
        fx = fminf(fmaxf(fx, 0.f), (float)(WW - 1));
        fy = fminf(fmaxf(fy, 0.f), (float)(HH - 1));
        float x0f = floorf(fx), y0f = floorf(fy);
        float wx = fx - x0f, wy = fy - y0f;
        int ix0 = (int)x0f, iy0 = (int)y0f;
        int ix1 = min(ix0 + 1, WW - 1);
        int iy1 = min(iy0 + 1, HH - 1);
        float w00 = (1.f - wy) * (1.f - wx);
        float w01 = (1.f - wy) * wx;
        float w10 = wy * (1.f - wx);
        float w11 = wy * wx;
        if (TR) {
            const float4* fmT = reinterpret_cast<const float4*>(fm);
            float4 v00 = fmT[iy0 * WW + ix0];
            float4 v01 = fmT[iy0 * WW + ix1];
            float4 v10 = fmT[iy1 * WW + ix0];
            float4 v11 = fmT[iy1 * WW + ix1];
            feat[p][0] = v00.x * w00 + v01.x * w01 + v10.x * w10 + v11.x * w11;
            feat[p][1] = v00.y * w00 + v01.y * w01 + v10.y * w10 + v11.y * w11;
            feat[p][2] = v00.z * w00 + v01.z * w01 + v10.z * w10 + v11.z * w11;
            feat[p][3] = v00.w * w00 + v01.w * w01 + v10.w * w10 + v11.w * w11;
        } else {
#pragma unroll
            for (int ch = 0; ch < 4; ++ch) {
                const float* f = fm + ch * HWSZ;
                feat[p][ch] = f[iy0 * WW + ix0] * w00 + f[iy0 * WW + ix1] * w01 +
                              f[iy1 * WW + ix0] * w10 + f[iy1 * WW + ix1] * w11;
            }
        }
    }

    // ---- MLP from LDS weights ----
    const float4* sW1v = reinterpret_cast<const float4*>(sW + O_W1);
    const float4* sB1v = reinterpret_cast<const float4*>(sW + O_B1);
    const float4* sW2v = reinterpret_cast<const float4*>(sW + O_W2);
    const float4* sB2v = reinterpret_cast<const float4*>(sW + O_B2);
    const float4* sW3v = reinterpret_cast<const float4*>(sW + O_W3);
    const float4* sB3v = reinterpret_cast<const float4*>(sW + O_B3);
    const float4* sW4v = reinterpret_cast<const float4*>(sW + O_W4);
    const float4* sB4v = reinterpret_cast<const float4*>(sW + O_B4);
    const float4* sW5v = reinterpret_cast<const float4*>(sW + O_W5);

    float in0[7] = {px[0][0], px[0][1], px[0][2], feat[0][0], feat[0][1], feat[0][2], feat[0][3]};
    float in1[7] = {px[1][0], px[1][1], px[1][2], feat[1][0], feat[1][1], feat[1][2], feat[1][3]};
    float h0[16], h1[16], g0[16], g1[16];

    // layer 1: 7 -> 16, relu  (jg = float4 column group)
#pragma unroll
    for (int jg = 0; jg < 4; ++jg) {
        float4 bb = sB1v[jg];
        float4 a0 = bb, a1 = bb;
#pragma unroll
        for (int k = 0; k < 7; ++k) {
            float4 w = sW1v[k * 4 + jg];
            float u0 = in0[k], u1 = in1[k];
            a0.x = fmaf(u0, w.x, a0.x); a1.x = fmaf(u1, w.x, a1.x);
            a0.y = fmaf(u0, w.y, a0.y); a1.y = fmaf(u1, w.y, a1.y);
            a0.z = fmaf(u0, w.z, a0.z); a1.z = fmaf(u1, w.z, a1.z);
            a0.w = fmaf(u0, w.w, a0.w); a1.w = fmaf(u1, w.w, a1.w);
        }
        h0[jg * 4 + 0] = fmaxf(a0.x, 0.f); h1[jg * 4 + 0] = fmaxf(a1.x, 0.f);
        h0[jg * 4 + 1] = fmaxf(a0.y, 0.f); h1[jg * 4 + 1] = fmaxf(a1.y, 0.f);
        h0[jg * 4 + 2] = fmaxf(a0.z, 0.f); h1[jg * 4 + 2] = fmaxf(a1.z, 0.f);
        h0[jg * 4 + 3] = fmaxf(a0.w, 0.f); h1[jg * 4 + 3] = fmaxf(a1.w, 0.f);
    }

#define LAYER16(WV, BV, src0, src1, dst0, dst1)                        \
    _Pragma("unroll")                                                  \
    for (int jg = 0; jg < 4; ++jg) {                                   \
        float4 bb = (BV)[jg];                                          \
        float4 a0 = bb, a1 = bb;                                       \
        _Pragma("unroll")                                              \
        for (int k = 0; k < 16; ++k) {                                 \
            float4 w = (WV)[k * 4 + jg];                               \
            float u0 = (src0)[k], u1 = (src1)[k];                      \
            a0.x = fmaf(u0, w.x, a0.x); a1.x = fmaf(u1, w.x, a1.x);    \
            a0.y = fmaf(u0, w.y, a0.y); a1.y = fmaf(u1, w.y, a1.y);    \
            a0.z = fmaf(u0, w.z, a0.z); a1.z = fmaf(u1, w.z, a1.z);    \
            a0.w = fmaf(u0, w.w, a0.w); a1.w = fmaf(u1, w.w, a1.w);    \
        }                                                              \
        (dst0)[jg * 4 + 0] = fmaxf(a0.x, 0.f); (dst1)[jg * 4 + 0] = fmaxf(a1.x, 0.f); \
        (dst0)[jg * 4 + 1] = fmaxf(a0.y, 0.f); (dst1)[jg * 4 + 1] = fmaxf(a1.y, 0.f); \
        (dst0)[jg * 4 + 2] = fmaxf(a0.z, 0.f); (dst1)[jg * 4 + 2] = fmaxf(a1.z, 0.f); \
        (dst0)[jg * 4 + 3] = fmaxf(a0.w, 0.f); (dst1)[jg * 4 + 3] = fmaxf(a1.w, 0.f); \
    }

    LAYER16(sW2v, sB2v, h0, h1, g0, g1)
    LAYER16(sW3v, sB3v, g0, g1, h0, h1)
    LAYER16(sW4v, sB4v, h0, h1, g0, g1)
#undef LAYER16

    // layer 5: 16 -> 3 (padded to 4), no relu
    float4 bb5 = *reinterpret_cast<const float4*>(sW + O_B5);
    float4 a0 = bb5, a1 = bb5;
#pragma unroll
    for (int k = 0; k < 16; ++k) {
        float4 w = sW5v[k];
        float u0 = g0[k], u1 = g1[k];
        a0.x = fmaf(u0, w.x, a0.x); a1.x = fmaf(u1, w.x, a1.x);
        a0.y = fmaf(u0, w.y, a0.y); a1.y = fmaf(u1, w.y, a1.y);
        a0.z = fmaf(u0, w.z, a0.z); a1.z = fmaf(u1, w.z, a1.z);
    }

    // ---- store ----
    if (have2) {
        float2* out2 = reinterpret_cast<float2*>(out);
        out2[3 * t]     = make_float2(a0.x, a0.y);
        out2[3 * t + 1] = make_float2(a0.z, a1.x);
        out2[3 * t + 2] = make_float2(a1.y, a1.z);
    } else {
        out[3 * i0] = a0.x; out[3 * i0 + 1] = a0.y; out[3 * i0 + 2] = a0.z;
    }
}

extern "C" void kernel_launch(void* const* d_in, const int* in_sizes, int n_in,
                              void* d_out, int out_size, void* d_ws, size_t ws_size,
                              hipStream_t stream) {
    const float* x  = (const float*)d_in[0];
    const float* fm = (const float*)d_in[1];
    const float* W1 = (const float*)d_in[2];
    const float* b1 = (const float*)d_in[3];
    const float* W2 = (const float*)d_in[4];
    const float* b2 = (const float*)d_in[5];
    const float* W3 = (const float*)d_in[6];
    const float* b3 = (const float*)d_in[7];
    const float* W4 = (const float*)d_in[8];
    const float* b4 = (const float*)d_in[9];
    const float* W5 = (const float*)d_in[10];
    const float* b5 = (const float*)d_in[11];
    float* out = (float*)d_out;

    const int n = in_sizes[0] / 3;  // 4,000,000 points
    const long long threads = ((long long)n + 1) / 2;
    const int block = 256;
    const int grid = (int)((threads + block - 1) / block);

    const size_t need = (size_t)HWSZ * 4 * sizeof(float);  // 4 MB
    if (ws_size >= need) {
        float* fmT = (float*)d_ws;
        fm_transpose<<<(HWSZ + 255) / 256, 256, 0, stream>>>(fm, fmT);
        mlp_fused<true><<<grid, block, 0, stream>>>(x, fmT, W1, b1, W2, b2, W3, b3,
                                                    W4, b4, W5, b5, out, n);
    } else {
        mlp_fused<false><<<grid, block, 0, stream>>>(x, fm, W1, b1, W2, b2, W3, b3,
                                                     W4, b4, W5, b5, out, n);
    }
}

// Round 5
// 244.077 us; speedup vs baseline: 8.7515x; 8.7515x over previous
//
#include <hip/hip_runtime.h>

#define HH 512
#define WW 512
#define HWSZ (HH * WW)

// LDS layout (float offsets). All float4-group bases are 16B-aligned.
#define O_W1 0      // 7x16
#define O_B1 112    // 16
#define O_W2 128    // 16x16
#define O_B2 384    // 16
#define O_W3 400    // 16x16
#define O_B3 656    // 16
#define O_W4 672    // 16x16
#define O_B4 928    // 16
#define O_W5 944    // 16x4 (padded from 16x3)
#define O_B5 1008   // 4 (padded from 3)
#define SW_TOT 1012

// Scheduler fence: NO instruction may be moved across (mask 0). Bounds the
// live range of each layer's ds_read weight loads. R4 proved that without
// this, the fully-unrolled body lets the scheduler hoist ALL ~1012 weight
// floats -> VGPR_Count=256 -> scratch spill (4.3 GB writes, 2096 us).
// Unlike asm volatile("":::"memory") (R3), it has no memory-clobber
// semantics, so it can't push the allocator into AGPR shuffling.
#define LAYER_FENCE() __builtin_amdgcn_sched_barrier(0)

// ---------------------------------------------------------------------------
// Pre-pass: transpose featuremap (C,H,W) -> (H,W,C): one bilinear corner = one
// aligned float4 load.
// ---------------------------------------------------------------------------
__global__ void fm_transpose(const float* __restrict__ fm, float* __restrict__ fmT) {
    int i = blockIdx.x * blockDim.x + threadIdx.x;
    if (i < HWSZ) {
        float4 v;
        v.x = fm[i];
        v.y = fm[HWSZ + i];
        v.z = fm[2 * HWSZ + i];
        v.w = fm[3 * HWSZ + i];
        reinterpret_cast<float4*>(fmT)[i] = v;
    }
}

// ---------------------------------------------------------------------------
// Fused grid_sample + MLP, 1 point/thread.
// Weights staged in LDS, read via uniform-address ds_read_b128 (broadcast,
// conflict-free, cannot be scalarized into SGPRs — R1/R3 showed global weight
// reads scalarize, blow the 102-SGPR budget, and trigger spill machinery).
// sched_barrier(0) between layers bounds weight live-range to <=68 floats.
// 1 point/thread keeps total pressure ~120 VGPR -> 4 waves/SIMD to hide the
// featuremap gather latency (~200-300 cyc, L2-resident 4 MB).
// ---------------------------------------------------------------------------
template <bool TR>
__global__ __launch_bounds__(256) void mlp_fused(
    const float* __restrict__ x, const float* __restrict__ fm,
    const float* __restrict__ W1, const float* __restrict__ b1,
    const float* __restrict__ W2, const float* __restrict__ b2,
    const float* __restrict__ W3, const float* __restrict__ b3,
    const float* __restrict__ W4, const float* __restrict__ b4,
    const float* __restrict__ W5, const float* __restrict__ b5,
    float* __restrict__ out, int n)
{
    __shared__ __align__(16) float sW[SW_TOT];
    const int tid = threadIdx.x;

    // ---- stage weights into LDS (one pass; 256 threads) ----
    if (tid < 112) sW[O_W1 + tid] = W1[tid];
    if (tid < 16) {
        sW[O_B1 + tid] = b1[tid];
        sW[O_B2 + tid] = b2[tid];
        sW[O_B3 + tid] = b3[tid];
        sW[O_B4 + tid] = b4[tid];
    }
    {   // W2/W3/W4: exactly one element per thread
        sW[O_W2 + tid] = W2[tid];
        sW[O_W3 + tid] = W3[tid];
        sW[O_W4 + tid] = W4[tid];
    }
    if (tid < 64) {  // W5 padded 16x3 -> 16x4
        int r = tid >> 2, c = tid & 3;
        sW[O_W5 + tid] = (c < 3) ? W5[r * 3 + c] : 0.f;
    }
    if (tid < 4) sW[O_B5 + tid] = (tid < 3) ? b5[tid] : 0.f;
    __syncthreads();

    const int i = blockIdx.x * blockDim.x + tid;
    if (i >= n) return;  // after the barrier: safe

    // ---- load point coords ----
    float p0 = x[3 * i], p1 = x[3 * i + 1], p2 = x[3 * i + 2];

    // ---- bilinear sample, border clamp (identical arithmetic to reference) ----
    float gx = p0 * 2.f - 1.f;
    float gy = p1 * 2.f - 1.f;
    float fx = ((gx + 1.f) * (float)WW - 1.f) * 0.5f;
    float fy = ((gy + 1.f) * (float)HH - 1.f) * 0.5f;
    fx = fminf(fmaxf(fx, 0.f), (float)(WW - 1));
    fy = fminf(fmaxf(fy, 0.f), (float)(HH - 1));
    float x0f = floorf(fx), y0f = floorf(fy);
    float wx = fx - x0f, wy = fy - y0f;
    int ix0 = (int)x0f, iy0 = (int)y0f;
    int ix1 = min(ix0 + 1, WW - 1);
    int iy1 = min(iy0 + 1, HH - 1);
    float w00 = (1.f - wy) * (1.f - wx);
    float w01 = (1.f - wy) * wx;
    float w10 = wy * (1.f - wx);
    float w11 = wy * wx;

    float feat[4];
    if (TR) {
        const float4* fmT = reinterpret_cast<const float4*>(fm);
        float4 v00 = fmT[iy0 * WW + ix0];
        float4 v01 = fmT[iy0 * WW + ix1];
        float4 v10 = fmT[iy1 * WW + ix0];
        float4 v11 = fmT[iy1 * WW + ix1];
        feat[0] = v00.x * w00 + v01.x * w01 + v10.x * w10 + v11.x * w11;
        feat[1] = v00.y * w00 + v01.y * w01 + v10.y * w10 + v11.y * w11;
        feat[2] = v00.z * w00 + v01.z * w01 + v10.z * w10 + v11.z * w11;
        feat[3] = v00.w * w00 + v01.w * w01 + v10.w * w10 + v11.w * w11;
    } else {
#pragma unroll
        for (int ch = 0; ch < 4; ++ch) {
            const float* f = fm + ch * HWSZ;
            feat[ch] = f[iy0 * WW + ix0] * w00 + f[iy0 * WW + ix1] * w01 +
                       f[iy1 * WW + ix0] * w10 + f[iy1 * WW + ix1] * w11;
        }
    }

    // ---- MLP from LDS weights, one layer at a time (fenced) ----
    const float4* sW1v = reinterpret_cast<const float4*>(sW + O_W1);
    const float4* sB1v = reinterpret_cast<const float4*>(sW + O_B1);
    const float4* sW2v = reinterpret_cast<const float4*>(sW + O_W2);
    const float4* sB2v = reinterpret_cast<const float4*>(sW + O_B2);
    const float4* sW3v = reinterpret_cast<const float4*>(sW + O_W3);
    const float4* sB3v = reinterpret_cast<const float4*>(sW + O_B3);
    const float4* sW4v = reinterpret_cast<const float4*>(sW + O_W4);
    const float4* sB4v = reinterpret_cast<const float4*>(sW + O_B4);
    const float4* sW5v = reinterpret_cast<const float4*>(sW + O_W5);

    float in[7] = {p0, p1, p2, feat[0], feat[1], feat[2], feat[3]};
    float h[16], g[16];

    LAYER_FENCE();
    // layer 1: 7 -> 16, relu
#pragma unroll
    for (int jg = 0; jg < 4; ++jg) {
        float4 a = sB1v[jg];
#pragma unroll
        for (int k = 0; k < 7; ++k) {
            float4 w = sW1v[k * 4 + jg];
            float u = in[k];
            a.x = fmaf(u, w.x, a.x);
            a.y = fmaf(u, w.y, a.y);
            a.z = fmaf(u, w.z, a.z);
            a.w = fmaf(u, w.w, a.w);
        }
        h[jg * 4 + 0] = fmaxf(a.x, 0.f);
        h[jg * 4 + 1] = fmaxf(a.y, 0.f);
        h[jg * 4 + 2] = fmaxf(a.z, 0.f);
        h[jg * 4 + 3] = fmaxf(a.w, 0.f);
    }
    LAYER_FENCE();

#define LAYER16(WV, BV, src, dst)                                      \
    _Pragma("unroll")                                                  \
    for (int jg = 0; jg < 4; ++jg) {                                   \
        float4 a = (BV)[jg];                                           \
        _Pragma("unroll")                                              \
        for (int k = 0; k < 16; ++k) {                                 \
            float4 w = (WV)[k * 4 + jg];                               \
            float u = (src)[k];                                        \
            a.x = fmaf(u, w.x, a.x);                                   \
            a.y = fmaf(u, w.y, a.y);                                   \
            a.z = fmaf(u, w.z, a.z);                                   \
            a.w = fmaf(u, w.w, a.w);                                   \
        }                                                              \
        (dst)[jg * 4 + 0] = fmaxf(a.x, 0.f);                           \
        (dst)[jg * 4 + 1] = fmaxf(a.y, 0.f);                           \
        (dst)[jg * 4 + 2] = fmaxf(a.z, 0.f);                           \
        (dst)[jg * 4 + 3] = fmaxf(a.w, 0.f);                           \
    }

    LAYER16(sW2v, sB2v, h, g)
    LAYER_FENCE();
    LAYER16(sW3v, sB3v, g, h)
    LAYER_FENCE();
    LAYER16(sW4v, sB4v, h, g)
    LAYER_FENCE();
#undef LAYER16

    // layer 5: 16 -> 3 (padded to 4), no relu
    float4 a5 = *reinterpret_cast<const float4*>(sW + O_B5);
#pragma unroll
    for (int k = 0; k < 16; ++k) {
        float4 w = sW5v[k];
        float u = g[k];
        a5.x = fmaf(u, w.x, a5.x);
        a5.y = fmaf(u, w.y, a5.y);
        a5.z = fmaf(u, w.z, a5.z);
    }

    // ---- store (12B/lane, contiguous across the wave) ----
    out[3 * i]     = a5.x;
    out[3 * i + 1] = a5.y;
    out[3 * i + 2] = a5.z;
}

extern "C" void kernel_launch(void* const* d_in, const int* in_sizes, int n_in,
                              void* d_out, int out_size, void* d_ws, size_t ws_size,
                              hipStream_t stream) {
    const float* x  = (const float*)d_in[0];
    const float* fm = (const float*)d_in[1];
    const float* W1 = (const float*)d_in[2];
    const float* b1 = (const float*)d_in[3];
    const float* W2 = (const float*)d_in[4];
    const float* b2 = (const float*)d_in[5];
    const float* W3 = (const float*)d_in[6];
    const float* b3 = (const float*)d_in[7];
    const float* W4 = (const float*)d_in[8];
    const float* b4 = (const float*)d_in[9];
    const float* W5 = (const float*)d_in[10];
    const float* b5 = (const float*)d_in[11];
    float* out = (float*)d_out;

    const int n = in_sizes[0] / 3;  // 4,000,000 points
    const int block = 256;
    const int grid = (n + block - 1) / block;

    const size_t need = (size_t)HWSZ * 4 * sizeof(float);  // 4 MB
    if (ws_size >= need) {
        float* fmT = (float*)d_ws;
        fm_transpose<<<(HWSZ + 255) / 256, 256, 0, stream>>>(fm, fmT);
        mlp_fused<true><<<grid, block, 0, stream>>>(x, fmT, W1, b1, W2, b2, W3, b3,
                                                    W4, b4, W5, b5, out, n);
    } else {
        mlp_fused<false><<<grid, block, 0, stream>>>(x, fm, W1, b1, W2, b2, W3, b3,
                                                     W4, b4, W5, b5, out, n);
    }
}